// Round 4
// baseline (320.240 us; speedup 1.0000x reference)
//
#include <hip/hip_runtime.h>

typedef __attribute__((ext_vector_type(8))) short short8;
typedef __attribute__((ext_vector_type(4))) float f32x4;

#define NB 8
#define NP 64
#define NS 256
#define ND 256
#define KH 128        // K-half per block
#define LSTR 136      // LDS row stride (bf16): 272 B, 16B-aligned for ds_read_b128

// round-to-nearest-even fp32 -> bf16 bits
__device__ __forceinline__ unsigned short f2bf(float f) {
    unsigned int u = __float_as_uint(f);
    u = (u + 0x7FFFu + ((u >> 16) & 1u)) >> 16;
    return (unsigned short)u;
}

// zero red/Sx/Sxx (ws is re-poisoned 0xAA before every launch)
__global__ __launch_bounds__(256) void k0_zero(float* __restrict__ ws) {
    reinterpret_cast<f32x4*>(ws)[(size_t)blockIdx.x * 256 + threadIdx.x] =
        f32x4{0.f, 0.f, 0.f, 0.f};
}

// K1: one wg (512 thr = 8 waves) per (b,p,K-half). X[b,p,:,128kh:128kh+128]
// staged bf16 in LDS; wave wv does score tiles (ib=(wv>>2)*2+pp, jb=wv&3),
// pp=0,1. Partial red/Sx/Sxx accumulated into global via atomicAdd.
// Sx via MFMA X*ones (no cross-lane ops in staging); Sxx = diag of scores.
__global__ __launch_bounds__(512, 4) void k1_gemm_red(
    const float* __restrict__ x, const float* __restrict__ w,
    float* __restrict__ red, float* __restrict__ Sx, float* __restrict__ Sxx)
{
    __shared__ unsigned short Xl[NS * LSTR];   // 69632 B
    __shared__ float red_l[4][NS];             // 4096 B

    const int t    = threadIdx.x;
    const int lane = t & 63;
    const int wv   = t >> 6;                   // 0..7
    const int p    = blockIdx.x & 63;
    const int b    = (blockIdx.x >> 6) & 7;
    const int kh   = blockIdx.x >> 9;          // 0,1

    const float* xb      = x + (size_t)(b * NP + p) * (NS * ND) + kh * KH;
    const size_t rowbase = (size_t)(b * NP + p) * NS;

    // ---- stage 256 rows x 128 floats fp32->bf16 (2 rows per wave-instr) ----
    const int r32 = t >> 5;                    // 0..15
    const int c32 = t & 31;                    // float4 col within the 128-chunk
    #pragma unroll 4
    for (int i = 0; i < 16; ++i) {
        const int row = 16 * i + r32;
        f32x4 v = *reinterpret_cast<const f32x4*>(xb + (size_t)row * ND + 4 * c32);
        unsigned long long pk =
              (unsigned long long)f2bf(v.x)
            | ((unsigned long long)f2bf(v.y) << 16)
            | ((unsigned long long)f2bf(v.z) << 32)
            | ((unsigned long long)f2bf(v.w) << 48);
        *reinterpret_cast<unsigned long long*>(&Xl[row * LSTR + 4 * c32]) = pk;
    }
    __syncthreads();

    const int qd = lane >> 4;
    const int c  = lane & 15;

    // ---- Sx (partial, this K-half) = X * ones via MFMA; no shuffles ----
    {
        const short8 ones = {0x3F80, 0x3F80, 0x3F80, 0x3F80,
                             0x3F80, 0x3F80, 0x3F80, 0x3F80};   // bf16 1.0
        #pragma unroll
        for (int h = 0; h < 2; ++h) {
            const int m = wv + 8 * h;          // 16-row slab
            f32x4 sacc = {0.f, 0.f, 0.f, 0.f};
            #pragma unroll
            for (int k0 = 0; k0 < KH; k0 += 32) {
                short8 afr = *reinterpret_cast<const short8*>(
                    &Xl[(16 * m + c) * LSTR + k0 + qd * 8]);
                sacc = __builtin_amdgcn_mfma_f32_16x16x32_bf16(afr, ones, sacc, 0, 0, 0);
            }
            if (c == 0) {                      // cols identical; row = 4qd+r
                #pragma unroll
                for (int r = 0; r < 4; ++r)
                    atomicAdd(&Sx[rowbase + 16 * m + 4 * qd + r], sacc[r]);
            }
        }
    }

    // ---- score tiles + weighted reduction ----
    const float* wp = w + (size_t)p * (NS * NS);
    #pragma unroll
    for (int pp = 0; pp < 2; ++pp) {
        const int ib = (wv >> 2) * 2 + pp;
        const int jb = wv & 3;
        f32x4 acc[4][4] = {};
        #pragma unroll
        for (int k0 = 0; k0 < KH; k0 += 32) {
            const int kof = k0 + qd * 8;
            short8 afr[4], bfr[4];
            #pragma unroll
            for (int i = 0; i < 4; ++i)
                afr[i] = *reinterpret_cast<const short8*>(
                    &Xl[(64 * ib + 16 * i + c) * LSTR + kof]);
            #pragma unroll
            for (int j = 0; j < 4; ++j)
                bfr[j] = *reinterpret_cast<const short8*>(
                    &Xl[(64 * jb + 16 * j + c) * LSTR + kof]);
            #pragma unroll
            for (int i = 0; i < 4; ++i)
                #pragma unroll
                for (int j = 0; j < 4; ++j)
                    acc[i][j] = __builtin_amdgcn_mfma_f32_16x16x32_bf16(
                        afr[i], bfr[j], acc[i][j], 0, 0, 0);
        }

        // Sxx (partial) = diag of this K-half's scores
        if (ib == jb && qd == (c >> 2)) {
            #pragma unroll
            for (int i = 0; i < 4; ++i)
                atomicAdd(&Sxx[rowbase + 64 * ib + 16 * i + c], acc[i][i][c & 3]);
        }

        // weighted reduction over this tile's 64 cols; C layout col=c, row=4qd+reg
        #pragma unroll
        for (int i = 0; i < 4; ++i) {
            #pragma unroll
            for (int r = 0; r < 4; ++r) {
                const int rl = 16 * i + 4 * qd + r;        // local row in [0,64)
                const float* wrow = wp + (size_t)(64 * ib + rl) * NS + 64 * jb + c;
                float s = acc[i][0][r] * wrow[0]
                        + acc[i][1][r] * wrow[16]
                        + acc[i][2][r] * wrow[32]
                        + acc[i][3][r] * wrow[48];
                #pragma unroll
                for (int off = 1; off < 16; off <<= 1)
                    s += __shfl_xor(s, off, 64);
                if (c == 0) red_l[jb][64 * ib + rl] = s;   // (jb,row) unique writer
            }
        }
    }
    __syncthreads();
    if (t < NS)
        atomicAdd(&red[rowbase + t],
                  (red_l[0][t] + red_l[1][t] + red_l[2][t] + red_l[3][t]) * 0.0625f);
}

// K2: per-channel BN stats -> scale/bias
__global__ __launch_bounds__(256) void k2_stats(
    const float* __restrict__ red, const float* __restrict__ Sx,
    const float* __restrict__ Sxx, const float* __restrict__ gamma,
    const float* __restrict__ beta, float* __restrict__ sb)
{
    __shared__ float l1[256], l2[256];
    const int p = blockIdx.x;
    const int t = threadIdx.x;
    float sy = 0.f, syy = 0.f;
    for (int n = t; n < NB * NS; n += 256) {
        int bb = n >> 8, s = n & 255;
        size_t idx = (size_t)(bb * NP + p) * NS + s;
        float r = red[idx], a = Sx[idx], q = Sxx[idx];
        sy  += a + 256.f * r;
        syy += q + 2.f * r * a + 256.f * r * r;
    }
    l1[t] = sy; l2[t] = syy;
    __syncthreads();
    for (int off = 128; off > 0; off >>= 1) {
        if (t < off) { l1[t] += l1[t + off]; l2[t] += l2[t + off]; }
        __syncthreads();
    }
    if (t == 0) {
        const float invN = 1.f / (float)(NB * NS * ND);
        float mean = l1[0] * invN;
        float var  = l2[0] * invN - mean * mean;
        float sc   = gamma[p] * rsqrtf(var + 1e-5f);
        sb[p]      = sc;
        sb[64 + p] = beta[p] - mean * sc;
    }
}

// K3: out = (x + red) * scale[p] + bias[p]; 4 float4 per thread
__global__ __launch_bounds__(256) void k3_norm(
    const float* __restrict__ x, const float* __restrict__ red,
    const float* __restrict__ sb, float* __restrict__ out)
{
    const size_t f0 = (size_t)blockIdx.x * 1024 + threadIdx.x;
    #pragma unroll
    for (int k = 0; k < 4; ++k) {
        const size_t f = f0 + (size_t)k * 256;             // float4 index
        f32x4 v = reinterpret_cast<const f32x4*>(x)[f];
        const float r  = red[f >> 6];                      // row = elem>>8 = f>>6
        const int   pp = (int)((f >> 14) & 63);
        v = (v + r) * sb[pp] + sb[64 + pp];
        reinterpret_cast<f32x4*>(out)[f] = v;
    }
}

extern "C" void kernel_launch(void* const* d_in, const int* in_sizes, int n_in,
                              void* d_out, int out_size, void* d_ws, size_t ws_size,
                              hipStream_t stream)
{
    const float* x     = (const float*)d_in[0];
    const float* w     = (const float*)d_in[1];
    const float* gamma = (const float*)d_in[2];
    const float* beta  = (const float*)d_in[3];
    float* out = (float*)d_out;

    float* red = (float*)d_ws;                  // NB*NP*NS floats
    float* Sx  = red + (size_t)NB * NP * NS;
    float* Sxx = Sx  + (size_t)NB * NP * NS;
    float* sb  = Sxx + (size_t)NB * NP * NS;    // 128 floats (scale, bias)

    // zero red/Sx/Sxx: 3*131072 floats = 393216 -> 384 blocks * 256 thr * 4
    hipLaunchKernelGGL(k0_zero, dim3(384), dim3(256), 0, stream, red);
    hipLaunchKernelGGL(k1_gemm_red, dim3(2 * NB * NP), dim3(512), 0, stream,
                       x, w, red, Sx, Sxx);
    hipLaunchKernelGGL(k2_stats, dim3(NP), dim3(256), 0, stream,
                       red, Sx, Sxx, gamma, beta, sb);
    hipLaunchKernelGGL(k3_norm, dim3((NB * NP * NS * ND) / (16 * 256)), dim3(256),
                       0, stream, x, red, sb, out);
}